// Round 2
// baseline (333.512 us; speedup 1.0000x reference)
//
#include <hip/hip_runtime.h>
#include <hip/hip_bf16.h>

#define B_    2
#define N_    2048
#define DIM_  512
#define H_    8
#define DH_   64
#define QKVW  1536          // 3*H*DH
#define BAND_ 128
#define LN_EPS 1e-5f

// ---------------- Kernel 1: LayerNorm -> f32 xn ----------------
// one block (256 threads) per row of 512
__global__ __launch_bounds__(256) void ln_kernel(const float* __restrict__ x,
                                                 const float* __restrict__ gamma,
                                                 const float* __restrict__ beta,
                                                 float* __restrict__ xn) {
    const int row = blockIdx.x;                  // 0..B*N-1
    const int tid = threadIdx.x;
    const float* xr = x + (size_t)row * DIM_;
    float2 v = *(const float2*)(xr + tid * 2);
    float s  = v.x + v.y;
    float sq = v.x * v.x + v.y * v.y;
    #pragma unroll
    for (int o = 32; o; o >>= 1) { s += __shfl_xor(s, o); sq += __shfl_xor(sq, o); }
    __shared__ float ss[4], ssq[4];
    const int wave = tid >> 6, lane = tid & 63;
    if (lane == 0) { ss[wave] = s; ssq[wave] = sq; }
    __syncthreads();
    s  = ss[0] + ss[1] + ss[2] + ss[3];
    sq = ssq[0] + ssq[1] + ssq[2] + ssq[3];
    const float mu  = s * (1.0f / DIM_);
    const float var = sq * (1.0f / DIM_) - mu * mu;
    const float rs  = rsqrtf(var + LN_EPS);
    float2 g = *(const float2*)(gamma + tid * 2);
    float2 b = *(const float2*)(beta  + tid * 2);
    float2 o;
    o.x = (v.x - mu) * rs * g.x + b.x;
    o.y = (v.y - mu) * rs * g.y + b.y;
    *(float2*)(xn + (size_t)row * DIM_ + tid * 2) = o;
}

// ---------------- Kernel 2: GEMM qkv = xn @ W (all f32) ----------------
#define BM 64
#define BN 64
#define BK 32
__global__ __launch_bounds__(256) void gemm_qkv(const float* __restrict__ A,  // [4096][512]
                                                const float* __restrict__ W,  // [512][1536]
                                                float* __restrict__ C) {      // [4096][1536]
    __shared__ float At[BK][BM + 4];   // k-major: At[k][m]
    __shared__ float Bs[BK][BN + 4];   // Bs[k][n]
    const int tid = threadIdx.x;
    const int tx = tid & 15, ty = tid >> 4;          // tx: n-quad, ty: m-quad
    const int row0 = blockIdx.y * BM, col0 = blockIdx.x * BN;
    float acc[4][4] = {};
    for (int k0 = 0; k0 < DIM_; k0 += BK) {
        // stage A: 64 rows x 32 k = 512 float4, transpose into At
        #pragma unroll
        for (int e = 0; e < 2; ++e) {
            const int idx4 = e * 256 + tid;          // 0..511
            const int r  = idx4 >> 3;                // 0..63
            const int kk = (idx4 & 7) * 4;           // 0..28
            float4 a = *(const float4*)(A + (size_t)(row0 + r) * DIM_ + k0 + kk);
            At[kk + 0][r] = a.x; At[kk + 1][r] = a.y;
            At[kk + 2][r] = a.z; At[kk + 3][r] = a.w;
        }
        // stage B: 32 x 64 f32, two float4 per thread
        #pragma unroll
        for (int e = 0; e < 2; ++e) {
            const int idx4 = e * 256 + tid;          // 0..511
            const int r = idx4 >> 4;                 // 0..31
            const int c = (idx4 & 15) * 4;
            *(float4*)&Bs[r][c] = *(const float4*)(W + (size_t)(k0 + r) * QKVW + col0 + c);
        }
        __syncthreads();
        #pragma unroll
        for (int kk = 0; kk < BK; ++kk) {
            float4 a = *(const float4*)&At[kk][ty * 4];
            float4 b = *(const float4*)&Bs[kk][tx * 4];
            acc[0][0] += a.x * b.x; acc[0][1] += a.x * b.y; acc[0][2] += a.x * b.z; acc[0][3] += a.x * b.w;
            acc[1][0] += a.y * b.x; acc[1][1] += a.y * b.y; acc[1][2] += a.y * b.z; acc[1][3] += a.y * b.w;
            acc[2][0] += a.z * b.x; acc[2][1] += a.z * b.y; acc[2][2] += a.z * b.z; acc[2][3] += a.z * b.w;
            acc[3][0] += a.w * b.x; acc[3][1] += a.w * b.y; acc[3][2] += a.w * b.z; acc[3][3] += a.w * b.w;
        }
        __syncthreads();
    }
    #pragma unroll
    for (int i = 0; i < 4; ++i) {
        float4 o = make_float4(acc[i][0], acc[i][1], acc[i][2], acc[i][3]);
        *(float4*)(C + (size_t)(row0 + ty * 4 + i) * QKVW + col0 + tx * 4) = o;
    }
}

// ---------------- Kernel 3: banded attention (f32) ----------------
// block = 256 threads (4 waves), handles (b, h, 64-query tile).
// Per wave: 16 queries; lane = key-slot for scores, lane = dim for PV acc.
#define LDSP 68   // padded stride
__global__ __launch_bounds__(256) void attn_kernel(const float* __restrict__ qkv,
                                                   float* __restrict__ out) {
    const int tile = blockIdx.x;   // 0..31
    const int h    = blockIdx.y;   // 0..7
    const int b    = blockIdx.z;   // 0..1
    const int i0   = tile * 64;
    const int tid  = threadIdx.x;
    const int lane = tid & 63;
    const int wave = tid >> 6;

    __shared__ float q_s[64][LDSP];   // q_s[qrow][d]
    __shared__ float kT_s[64][LDSP];  // kT_s[d][key]
    __shared__ float v_s[64][LDSP];   // v_s[key][d]

    const size_t base = ((size_t)b * N_) * QKVW + (size_t)h * DH_;

    // stage Q tile: 1024 float4 slots, 4 per thread
    #pragma unroll
    for (int e = 0; e < 4; ++e) {
        const int lin4 = e * 256 + tid;          // 0..1023
        const int r  = lin4 >> 4;                // 0..63
        const int d4 = (lin4 & 15) * 4;          // 0..60
        float4 f = *(const float4*)(qkv + base + (size_t)(i0 + r) * QKVW + d4);
        *(float4*)&q_s[r][d4] = f;
    }

    float m_run[16], l_run[16], acc[16];
    #pragma unroll
    for (int q = 0; q < 16; ++q) { m_run[q] = -1e30f; l_run[q] = 0.0f; acc[q] = 0.0f; }

    #pragma unroll 1
    for (int c = 0; c < 5; ++c) {
        const int jbase = i0 - 128 + c * 64;
        if (jbase + 64 <= 0 || jbase >= N_) continue;   // uniform per block
        __syncthreads();
        // stage K (transposed) and V for keys [jbase, jbase+64)
        #pragma unroll
        for (int e = 0; e < 4; ++e) {
            const int lin4 = e * 256 + tid;
            const int r  = lin4 >> 4;
            const int d4 = (lin4 & 15) * 4;
            const int j  = jbase + r;
            float4 kf = make_float4(0.f, 0.f, 0.f, 0.f);
            float4 vf = make_float4(0.f, 0.f, 0.f, 0.f);
            if (j >= 0 && j < N_) {
                kf = *(const float4*)(qkv + base + (size_t)j * QKVW + 512 + d4);
                vf = *(const float4*)(qkv + base + (size_t)j * QKVW + 1024 + d4);
            }
            kT_s[d4 + 0][r] = kf.x; kT_s[d4 + 1][r] = kf.y;
            kT_s[d4 + 2][r] = kf.z; kT_s[d4 + 3][r] = kf.w;
            *(float4*)&v_s[r][d4] = vf;
        }
        __syncthreads();

        #pragma unroll
        for (int q = 0; q < 16; ++q) {
            const int qi = wave * 16 + q;
            const int i  = i0 + qi;
            const int blo = (i - BAND_ < 0) ? 0 : i - BAND_;
            const int bhi = (i + BAND_ > N_) ? N_ : i + BAND_;
            if (jbase >= bhi || jbase + 64 <= blo) continue;  // uniform per wave
            const int j = jbase + lane;
            const bool valid = (j >= blo) && (j < bhi);
            float s0 = 0.f, s1 = 0.f, s2 = 0.f, s3 = 0.f;
            #pragma unroll 1
            for (int db = 0; db < 64; db += 16) {
                float4 qa = *(const float4*)&q_s[qi][db + 0];
                float4 qb = *(const float4*)&q_s[qi][db + 4];
                float4 qc = *(const float4*)&q_s[qi][db + 8];
                float4 qd = *(const float4*)&q_s[qi][db + 12];
                s0 += qa.x * kT_s[db + 0][lane];  s1 += qa.y * kT_s[db + 1][lane];
                s2 += qa.z * kT_s[db + 2][lane];  s3 += qa.w * kT_s[db + 3][lane];
                s0 += qb.x * kT_s[db + 4][lane];  s1 += qb.y * kT_s[db + 5][lane];
                s2 += qb.z * kT_s[db + 6][lane];  s3 += qb.w * kT_s[db + 7][lane];
                s0 += qc.x * kT_s[db + 8][lane];  s1 += qc.y * kT_s[db + 9][lane];
                s2 += qc.z * kT_s[db + 10][lane]; s3 += qc.w * kT_s[db + 11][lane];
                s0 += qd.x * kT_s[db + 12][lane]; s1 += qd.y * kT_s[db + 13][lane];
                s2 += qd.z * kT_s[db + 14][lane]; s3 += qd.w * kT_s[db + 15][lane];
            }
            float s = (s0 + s1) + (s2 + s3);
            s = valid ? s : -1e30f;
            float m_c = s;
            #pragma unroll
            for (int o = 32; o; o >>= 1) m_c = fmaxf(m_c, __shfl_xor(m_c, o));
            const float m_new = fmaxf(m_run[q], m_c);
            const float alpha = __expf(m_run[q] - m_new);
            const float p = valid ? __expf(s - m_new) : 0.0f;
            float l_c = p;
            #pragma unroll
            for (int o = 32; o; o >>= 1) l_c += __shfl_xor(l_c, o);
            l_run[q] = l_run[q] * alpha + l_c;
            float a0 = 0.f, a1 = 0.f, a2 = 0.f, a3 = 0.f;
            #pragma unroll 1
            for (int l = 0; l < 64; l += 4) {
                a0 += __shfl(p, l + 0) * v_s[l + 0][lane];
                a1 += __shfl(p, l + 1) * v_s[l + 1][lane];
                a2 += __shfl(p, l + 2) * v_s[l + 2][lane];
                a3 += __shfl(p, l + 3) * v_s[l + 3][lane];
            }
            acc[q] = acc[q] * alpha + ((a0 + a1) + (a2 + a3));
            m_run[q] = m_new;
        }
    }

    // epilogue: normalize and write [B,N,H*DH] f32
    #pragma unroll
    for (int q = 0; q < 16; ++q) {
        const int i = i0 + wave * 16 + q;
        out[((size_t)b * N_ + i) * DIM_ + h * DH_ + lane] = acc[q] / l_run[q];
    }
}

extern "C" void kernel_launch(void* const* d_in, const int* in_sizes, int n_in,
                              void* d_out, int out_size, void* d_ws, size_t ws_size,
                              hipStream_t stream) {
    const float* x     = (const float*)d_in[0];
    const float* w     = (const float*)d_in[1];
    const float* gamma = (const float*)d_in[2];
    const float* beta  = (const float*)d_in[3];
    float* out = (float*)d_out;

    float* xnf  = (float*)d_ws;                                // 4096*512  f32 =  8.4 MB
    float* qkvf = xnf + (size_t)B_ * N_ * DIM_;                // 4096*1536 f32 = 25.2 MB

    ln_kernel<<<dim3(B_ * N_), dim3(256), 0, stream>>>(x, gamma, beta, xnf);
    gemm_qkv<<<dim3(QKVW / BN, (B_ * N_) / BM), dim3(256), 0, stream>>>(xnf, w, qkvf);
    attn_kernel<<<dim3(N_ / 64, H_, B_), dim3(256), 0, stream>>>(qkvf, out);
}

// Round 3
// 158.985 us; speedup vs baseline: 2.0978x; 2.0978x over previous
//
#include <hip/hip_runtime.h>
#include <hip/hip_bf16.h>

#define B_    2
#define N_    2048
#define DIM_  512
#define H_    8
#define DH_   64
#define QKVW  1536          // 3*H*DH
#define BAND_ 128
#define LN_EPS 1e-5f

__device__ __forceinline__ float bf2f(unsigned short u) {
    union { unsigned int i; float f; } w; w.i = ((unsigned int)u) << 16; return w.f;
}
__device__ __forceinline__ unsigned short f2bf(float f) {
    __hip_bfloat16 h = __float2bfloat16(f);
    return *reinterpret_cast<unsigned short*>(&h);
}

// ---------------- Kernel 1: LayerNorm -> f32 xn ----------------
__global__ __launch_bounds__(256) void ln_kernel(const float* __restrict__ x,
                                                 const float* __restrict__ gamma,
                                                 const float* __restrict__ beta,
                                                 float* __restrict__ xn) {
    const int row = blockIdx.x;
    const int tid = threadIdx.x;
    const float* xr = x + (size_t)row * DIM_;
    float2 v = *(const float2*)(xr + tid * 2);
    float s  = v.x + v.y;
    float sq = v.x * v.x + v.y * v.y;
    #pragma unroll
    for (int o = 32; o; o >>= 1) { s += __shfl_xor(s, o); sq += __shfl_xor(sq, o); }
    __shared__ float ss[4], ssq[4];
    const int wave = tid >> 6, lane = tid & 63;
    if (lane == 0) { ss[wave] = s; ssq[wave] = sq; }
    __syncthreads();
    s  = ss[0] + ss[1] + ss[2] + ss[3];
    sq = ssq[0] + ssq[1] + ssq[2] + ssq[3];
    const float mu  = s * (1.0f / DIM_);
    const float var = sq * (1.0f / DIM_) - mu * mu;
    const float rs  = rsqrtf(var + LN_EPS);
    float2 g = *(const float2*)(gamma + tid * 2);
    float2 b = *(const float2*)(beta  + tid * 2);
    float2 o;
    o.x = (v.x - mu) * rs * g.x + b.x;
    o.y = (v.y - mu) * rs * g.y + b.y;
    *(float2*)(xn + (size_t)row * DIM_ + tid * 2) = o;
}

// ---------------- Kernel 2: GEMM qkv = xn @ W (all f32) ----------------
#define BM 64
#define BN 64
#define BK 32
__global__ __launch_bounds__(256) void gemm_qkv(const float* __restrict__ A,
                                                const float* __restrict__ W,
                                                float* __restrict__ C) {
    __shared__ float At[BK][BM + 4];
    __shared__ float Bs[BK][BN + 4];
    const int tid = threadIdx.x;
    const int tx = tid & 15, ty = tid >> 4;
    const int row0 = blockIdx.y * BM, col0 = blockIdx.x * BN;
    float acc[4][4] = {};
    for (int k0 = 0; k0 < DIM_; k0 += BK) {
        #pragma unroll
        for (int e = 0; e < 2; ++e) {
            const int idx4 = e * 256 + tid;
            const int r  = idx4 >> 3;
            const int kk = (idx4 & 7) * 4;
            float4 a = *(const float4*)(A + (size_t)(row0 + r) * DIM_ + k0 + kk);
            At[kk + 0][r] = a.x; At[kk + 1][r] = a.y;
            At[kk + 2][r] = a.z; At[kk + 3][r] = a.w;
        }
        #pragma unroll
        for (int e = 0; e < 2; ++e) {
            const int idx4 = e * 256 + tid;
            const int r = idx4 >> 4;
            const int c = (idx4 & 15) * 4;
            *(float4*)&Bs[r][c] = *(const float4*)(W + (size_t)(k0 + r) * QKVW + col0 + c);
        }
        __syncthreads();
        #pragma unroll
        for (int kk = 0; kk < BK; ++kk) {
            float4 a = *(const float4*)&At[kk][ty * 4];
            float4 b = *(const float4*)&Bs[kk][tx * 4];
            acc[0][0] += a.x * b.x; acc[0][1] += a.x * b.y; acc[0][2] += a.x * b.z; acc[0][3] += a.x * b.w;
            acc[1][0] += a.y * b.x; acc[1][1] += a.y * b.y; acc[1][2] += a.y * b.z; acc[1][3] += a.y * b.w;
            acc[2][0] += a.z * b.x; acc[2][1] += a.z * b.y; acc[2][2] += a.z * b.z; acc[2][3] += a.z * b.w;
            acc[3][0] += a.w * b.x; acc[3][1] += a.w * b.y; acc[3][2] += a.w * b.z; acc[3][3] += a.w * b.w;
        }
        __syncthreads();
    }
    #pragma unroll
    for (int i = 0; i < 4; ++i) {
        float4 o = make_float4(acc[i][0], acc[i][1], acc[i][2], acc[i][3]);
        *(float4*)(C + (size_t)(row0 + ty * 4 + i) * QKVW + col0 + tx * 4) = o;
    }
}

// ---------------- Kernel 3: banded attention, LDS-GEMM form ----------------
// block = 256 threads, handles (b, h, 64-query tile). Per thread: 4x4 S tile,
// 4x4 O tile (rows m0..m0+3, cols/dims n0..n0+3). Softmax in registers via
// 16-lane shfl_xor row groups. K tile XOR-swizzled (read walks 4*tx rows).
__global__ __launch_bounds__(256) void attn_kernel(const float* __restrict__ qkv,
                                                   float* __restrict__ out) {
    const int tile = blockIdx.x;   // 0..31
    const int h    = blockIdx.y;   // 0..7
    const int b    = blockIdx.z;   // 0..1
    const int i0   = tile * 64;
    const int tid  = threadIdx.x;
    const int tx   = tid & 15, ty = tid >> 4;
    const int m0   = ty * 4, n0 = tx * 4;

    __shared__ float          q_s[64][64];   // [row][d]
    __shared__ float          k_s[64][64];   // [key][d], slot-swizzled: phys = d4 ^ (key>>2)
    __shared__ float          v_s[64][64];   // [key][d]
    __shared__ unsigned short p_s[64][64];   // [row][key], bf16

    const size_t base = ((size_t)b * N_) * QKVW + (size_t)h * DH_;

    // stage Q tile
    #pragma unroll
    for (int e = 0; e < 4; ++e) {
        const int lin4 = e * 256 + tid;
        const int r  = lin4 >> 4;
        const int sl = lin4 & 15;
        float4 f = *(const float4*)(qkv + base + (size_t)(i0 + r) * QKVW + sl * 4);
        *(float4*)&q_s[r][sl * 4] = f;
    }

    float m_run[4], l_run[4], oacc[4][4];
    #pragma unroll
    for (int i = 0; i < 4; ++i) {
        m_run[i] = -1e30f; l_run[i] = 0.0f;
        #pragma unroll
        for (int j = 0; j < 4; ++j) oacc[i][j] = 0.0f;
    }

    #pragma unroll 1
    for (int c = 0; c < 5; ++c) {
        const int jbase = i0 - 128 + c * 64;
        if (jbase + 64 <= 0 || jbase >= N_) continue;   // uniform per block
        __syncthreads();
        // stage K (swizzled) and V
        #pragma unroll
        for (int e = 0; e < 4; ++e) {
            const int lin4 = e * 256 + tid;
            const int r  = lin4 >> 4;
            const int sl = lin4 & 15;
            const int j  = jbase + r;
            float4 kf = make_float4(0.f, 0.f, 0.f, 0.f);
            float4 vf = make_float4(0.f, 0.f, 0.f, 0.f);
            if (j >= 0 && j < N_) {
                kf = *(const float4*)(qkv + base + (size_t)j * QKVW + 512 + sl * 4);
                vf = *(const float4*)(qkv + base + (size_t)j * QKVW + 1024 + sl * 4);
            }
            *(float4*)&k_s[r][((sl ^ (r >> 2)) & 15) * 4] = kf;
            *(float4*)&v_s[r][sl * 4] = vf;
        }
        __syncthreads();

        // ---- S = Q K^T, 4x4 per thread ----
        float s[4][4] = {};
        #pragma unroll 4
        for (int d4 = 0; d4 < 16; ++d4) {
            const int ksl = ((d4 ^ tx) & 15) * 4;   // (n0+j)>>2 == tx for j<4
            float4 qa[4], kb[4];
            #pragma unroll
            for (int i = 0; i < 4; ++i) qa[i] = *(const float4*)&q_s[m0 + i][d4 * 4];
            #pragma unroll
            for (int j = 0; j < 4; ++j) kb[j] = *(const float4*)&k_s[n0 + j][ksl];
            #pragma unroll
            for (int i = 0; i < 4; ++i)
                #pragma unroll
                for (int j = 0; j < 4; ++j)
                    s[i][j] += qa[i].x * kb[j].x + qa[i].y * kb[j].y
                             + qa[i].z * kb[j].z + qa[i].w * kb[j].w;
        }

        // ---- online softmax (registers + 16-lane shfl groups) ----
        #pragma unroll
        for (int i = 0; i < 4; ++i) {
            const int gm = i0 + m0 + i;
            bool val[4];
            float mx = -1e30f;
            #pragma unroll
            for (int j = 0; j < 4; ++j) {
                const int gj = jbase + n0 + j;
                const int d  = gj - gm;
                val[j] = (gj >= 0) && (gj < N_) && (d >= -BAND_) && (d < BAND_);
                s[i][j] = val[j] ? s[i][j] : -1e30f;
                mx = fmaxf(mx, s[i][j]);
            }
            #pragma unroll
            for (int o = 1; o < 16; o <<= 1) mx = fmaxf(mx, __shfl_xor(mx, o));
            const float m_new = fmaxf(m_run[i], mx);
            const float alpha = __expf(m_run[i] - m_new);
            float p[4], l_c = 0.f;
            #pragma unroll
            for (int j = 0; j < 4; ++j) {
                p[j] = val[j] ? __expf(s[i][j] - m_new) : 0.0f;
                l_c += p[j];
            }
            #pragma unroll
            for (int o = 1; o < 16; o <<= 1) l_c += __shfl_xor(l_c, o);
            l_run[i] = l_run[i] * alpha + l_c;
            m_run[i] = m_new;
            #pragma unroll
            for (int j = 0; j < 4; ++j) oacc[i][j] *= alpha;
            ushort4 pu;
            pu.x = f2bf(p[0]); pu.y = f2bf(p[1]); pu.z = f2bf(p[2]); pu.w = f2bf(p[3]);
            *(ushort4*)&p_s[m0 + i][n0] = pu;
        }
        __syncthreads();

        // ---- O += P V, 4x4 per thread (dims n0..n0+3) ----
        #pragma unroll 4
        for (int k4 = 0; k4 < 16; ++k4) {
            float4 vb[4];
            #pragma unroll
            for (int t = 0; t < 4; ++t) vb[t] = *(const float4*)&v_s[k4 * 4 + t][n0];
            #pragma unroll
            for (int i = 0; i < 4; ++i) {
                const ushort4 pu = *(const ushort4*)&p_s[m0 + i][k4 * 4];
                const float pf[4] = { bf2f(pu.x), bf2f(pu.y), bf2f(pu.z), bf2f(pu.w) };
                #pragma unroll
                for (int t = 0; t < 4; ++t) {
                    oacc[i][0] += pf[t] * vb[t].x;
                    oacc[i][1] += pf[t] * vb[t].y;
                    oacc[i][2] += pf[t] * vb[t].z;
                    oacc[i][3] += pf[t] * vb[t].w;
                }
            }
        }
    }

    // epilogue
    #pragma unroll
    for (int i = 0; i < 4; ++i) {
        const float inv = 1.0f / l_run[i];
        float4 o = make_float4(oacc[i][0] * inv, oacc[i][1] * inv,
                               oacc[i][2] * inv, oacc[i][3] * inv);
        *(float4*)(out + ((size_t)b * N_ + i0 + m0 + i) * DIM_ + h * DH_ + n0) = o;
    }
}

extern "C" void kernel_launch(void* const* d_in, const int* in_sizes, int n_in,
                              void* d_out, int out_size, void* d_ws, size_t ws_size,
                              hipStream_t stream) {
    const float* x     = (const float*)d_in[0];
    const float* w     = (const float*)d_in[1];
    const float* gamma = (const float*)d_in[2];
    const float* beta  = (const float*)d_in[3];
    float* out = (float*)d_out;

    float* xnf  = (float*)d_ws;
    float* qkvf = xnf + (size_t)B_ * N_ * DIM_;

    ln_kernel<<<dim3(B_ * N_), dim3(256), 0, stream>>>(x, gamma, beta, xnf);
    gemm_qkv<<<dim3(QKVW / BN, (B_ * N_) / BM), dim3(256), 0, stream>>>(xnf, w, qkvf);
    attn_kernel<<<dim3(N_ / 64, H_, B_), dim3(256), 0, stream>>>(qkvf, out);
}

// Round 5
// 104.106 us; speedup vs baseline: 3.2036x; 1.5271x over previous
//
#include <hip/hip_runtime.h>
#include <hip/hip_bf16.h>

#define B_    2
#define N_    2048
#define DIM_  512
#define H_    8
#define DH_   64
#define QKVW  1536          // 3*H*DH
#define BAND_ 128
#define LN_EPS 1e-5f

typedef __attribute__((ext_vector_type(8))) short bf16x8;
typedef __attribute__((ext_vector_type(4))) float f32x4;
typedef __attribute__((ext_vector_type(8))) unsigned short ushort8;

__device__ __forceinline__ float bf2f(unsigned short u) {
    union { unsigned int i; float f; } w; w.i = ((unsigned int)u) << 16; return w.f;
}
__device__ __forceinline__ unsigned short f2bf(float f) {
    __hip_bfloat16 h = __float2bfloat16(f);
    return *reinterpret_cast<unsigned short*>(&h);
}

// ---------------- Kernel 1: LayerNorm -> split bf16 (hi, lo) ----------------
__global__ __launch_bounds__(256) void ln_kernel(const float* __restrict__ x,
                                                 const float* __restrict__ gamma,
                                                 const float* __restrict__ beta,
                                                 unsigned short* __restrict__ xh,
                                                 unsigned short* __restrict__ xl) {
    const int row = blockIdx.x;
    const int tid = threadIdx.x;
    const float* xr = x + (size_t)row * DIM_;
    float2 v = *(const float2*)(xr + tid * 2);
    float s  = v.x + v.y;
    float sq = v.x * v.x + v.y * v.y;
    #pragma unroll
    for (int o = 32; o; o >>= 1) { s += __shfl_xor(s, o); sq += __shfl_xor(sq, o); }
    __shared__ float ss[4], ssq[4];
    const int wave = tid >> 6, lane = tid & 63;
    if (lane == 0) { ss[wave] = s; ssq[wave] = sq; }
    __syncthreads();
    s  = ss[0] + ss[1] + ss[2] + ss[3];
    sq = ssq[0] + ssq[1] + ssq[2] + ssq[3];
    const float mu  = s * (1.0f / DIM_);
    const float var = sq * (1.0f / DIM_) - mu * mu;
    const float rs  = rsqrtf(var + LN_EPS);
    float2 g = *(const float2*)(gamma + tid * 2);
    float2 b = *(const float2*)(beta  + tid * 2);
    float y0 = (v.x - mu) * rs * g.x + b.x;
    float y1 = (v.y - mu) * rs * g.y + b.y;
    ushort2 h, l;
    h.x = f2bf(y0); l.x = f2bf(y0 - bf2f(h.x));
    h.y = f2bf(y1); l.y = f2bf(y1 - bf2f(h.y));
    *(ushort2*)(xh + (size_t)row * DIM_ + tid * 2) = h;
    *(ushort2*)(xl + (size_t)row * DIM_ + tid * 2) = l;
}

// ---------------- Kernel 1b: W [512][1536] -> W^T split bf16 [1536][512] ----------------
__global__ __launch_bounds__(256) void wsplit_kernel(const float* __restrict__ W,
                                                     unsigned short* __restrict__ Bh,
                                                     unsigned short* __restrict__ Bl) {
    __shared__ float T[64][65];
    const int n0 = blockIdx.x * 64, k0 = blockIdx.y * 64;
    const int tid = threadIdx.x;
    #pragma unroll
    for (int e = 0; e < 4; ++e) {
        const int lin = e * 256 + tid;       // 0..1023
        const int kk = lin >> 4;             // 0..63
        const int n4 = (lin & 15) * 4;
        float4 f = *(const float4*)(W + (size_t)(k0 + kk) * QKVW + n0 + n4);
        T[kk][n4 + 0] = f.x; T[kk][n4 + 1] = f.y;
        T[kk][n4 + 2] = f.z; T[kk][n4 + 3] = f.w;
    }
    __syncthreads();
    #pragma unroll
    for (int e = 0; e < 4; ++e) {
        const int lin = e * 256 + tid;
        const int nn = lin >> 4;             // 0..63
        const int kq = (lin & 15) * 4;       // 0..60
        ushort4 h, l;
        float f;
        f = T[kq + 0][nn]; h.x = f2bf(f); l.x = f2bf(f - bf2f(h.x));
        f = T[kq + 1][nn]; h.y = f2bf(f); l.y = f2bf(f - bf2f(h.y));
        f = T[kq + 2][nn]; h.z = f2bf(f); l.z = f2bf(f - bf2f(h.z));
        f = T[kq + 3][nn]; h.w = f2bf(f); l.w = f2bf(f - bf2f(h.w));
        *(ushort4*)(Bh + (size_t)(n0 + nn) * DIM_ + k0 + kq) = h;
        *(ushort4*)(Bl + (size_t)(n0 + nn) * DIM_ + k0 + kq) = l;
    }
}

// ---------------- Kernel 2: MFMA GEMM, 3-pass split-bf16 ----------------
// C[4096][1536] f32 = (Ah+Al)(Bh+Bl)^T dropping lo*lo. 128x128 tile, 4 waves 2x2.
// LDS tiles [128][32] bf16 LINEAR (64B rows: fragment reads already at the
// 8-dword/bank floor since k-block varies with lane>>4 — no swizzle needed).
__global__ __launch_bounds__(256) void gemm_mfma(const unsigned short* __restrict__ Ah,
                                                 const unsigned short* __restrict__ Al,
                                                 const unsigned short* __restrict__ Bh,
                                                 const unsigned short* __restrict__ Bl,
                                                 float* __restrict__ C) {
    __shared__ unsigned short sAh[128 * 32], sAl[128 * 32];
    __shared__ unsigned short sBh[128 * 32], sBl[128 * 32];
    const int tid  = threadIdx.x;
    const int lane = tid & 63, wave = tid >> 6;
    const int wr = wave >> 1, wc = wave & 1;
    const int row0 = blockIdx.y * 128;
    const int col0 = blockIdx.x * 128;

    f32x4 acc[4][4] = {};

    for (int k0 = 0; k0 < DIM_; k0 += 32) {
        __syncthreads();
        // stage: 128 rows x 32 k bf16 per array; 512 ushort8 slots, 2 per thread
        #pragma unroll
        for (int e = 0; e < 2; ++e) {
            const int idx = e * 256 + tid;       // 0..511
            const int r   = idx >> 2;            // 0..127
            const int k8  = (idx & 3) * 8;       // 0,8,16,24
            const int sidx = r * 32 + k8;
            *(ushort8*)&sAh[sidx] = *(const ushort8*)(Ah + (size_t)(row0 + r) * DIM_ + k0 + k8);
            *(ushort8*)&sAl[sidx] = *(const ushort8*)(Al + (size_t)(row0 + r) * DIM_ + k0 + k8);
            *(ushort8*)&sBh[sidx] = *(const ushort8*)(Bh + (size_t)(col0 + r) * DIM_ + k0 + k8);
            *(ushort8*)&sBl[sidx] = *(const ushort8*)(Bl + (size_t)(col0 + r) * DIM_ + k0 + k8);
        }
        __syncthreads();

        const int kb = (lane >> 4) * 8;
        bf16x8 ah[4], al[4], bh[4], bl[4];
        #pragma unroll
        for (int mi = 0; mi < 4; ++mi) {
            const int r = wr * 64 + mi * 16 + (lane & 15);
            ah[mi] = *(const bf16x8*)&sAh[r * 32 + kb];
            al[mi] = *(const bf16x8*)&sAl[r * 32 + kb];
        }
        #pragma unroll
        for (int ni = 0; ni < 4; ++ni) {
            const int r = wc * 64 + ni * 16 + (lane & 15);
            bh[ni] = *(const bf16x8*)&sBh[r * 32 + kb];
            bl[ni] = *(const bf16x8*)&sBl[r * 32 + kb];
        }
        #pragma unroll
        for (int mi = 0; mi < 4; ++mi)
            #pragma unroll
            for (int ni = 0; ni < 4; ++ni) {
                acc[mi][ni] = __builtin_amdgcn_mfma_f32_16x16x32_bf16(ah[mi], bh[ni], acc[mi][ni], 0, 0, 0);
                acc[mi][ni] = __builtin_amdgcn_mfma_f32_16x16x32_bf16(al[mi], bh[ni], acc[mi][ni], 0, 0, 0);
                acc[mi][ni] = __builtin_amdgcn_mfma_f32_16x16x32_bf16(ah[mi], bl[ni], acc[mi][ni], 0, 0, 0);
            }
    }

    // epilogue: C/D layout col = lane&15, row = (lane>>4)*4 + reg  [m89]
    #pragma unroll
    for (int mi = 0; mi < 4; ++mi)
        #pragma unroll
        for (int ni = 0; ni < 4; ++ni) {
            const int col   = col0 + wc * 64 + ni * 16 + (lane & 15);
            const int rbase = row0 + wr * 64 + mi * 16 + (lane >> 4) * 4;
            #pragma unroll
            for (int r = 0; r < 4; ++r)
                C[(size_t)(rbase + r) * QKVW + col] = acc[mi][ni][r];
        }
}

// ---------------- Kernel 3: banded attention, LDS-GEMM form (unchanged) ----------------
__global__ __launch_bounds__(256) void attn_kernel(const float* __restrict__ qkv,
                                                   float* __restrict__ out) {
    const int tile = blockIdx.x;
    const int h    = blockIdx.y;
    const int b    = blockIdx.z;
    const int i0   = tile * 64;
    const int tid  = threadIdx.x;
    const int tx   = tid & 15, ty = tid >> 4;
    const int m0   = ty * 4, n0 = tx * 4;

    __shared__ float          q_s[64][64];
    __shared__ float          k_s[64][64];   // slot-swizzled: phys = d4 ^ (key>>2)
    __shared__ float          v_s[64][64];
    __shared__ unsigned short p_s[64][64];

    const size_t base = ((size_t)b * N_) * QKVW + (size_t)h * DH_;

    #pragma unroll
    for (int e = 0; e < 4; ++e) {
        const int lin4 = e * 256 + tid;
        const int r  = lin4 >> 4;
        const int sl = lin4 & 15;
        float4 f = *(const float4*)(qkv + base + (size_t)(i0 + r) * QKVW + sl * 4);
        *(float4*)&q_s[r][sl * 4] = f;
    }

    float m_run[4], l_run[4], oacc[4][4];
    #pragma unroll
    for (int i = 0; i < 4; ++i) {
        m_run[i] = -1e30f; l_run[i] = 0.0f;
        #pragma unroll
        for (int j = 0; j < 4; ++j) oacc[i][j] = 0.0f;
    }

    #pragma unroll 1
    for (int c = 0; c < 5; ++c) {
        const int jbase = i0 - 128 + c * 64;
        if (jbase + 64 <= 0 || jbase >= N_) continue;
        __syncthreads();
        #pragma unroll
        for (int e = 0; e < 4; ++e) {
            const int lin4 = e * 256 + tid;
            const int r  = lin4 >> 4;
            const int sl = lin4 & 15;
            const int j  = jbase + r;
            float4 kf = make_float4(0.f, 0.f, 0.f, 0.f);
            float4 vf = make_float4(0.f, 0.f, 0.f, 0.f);
            if (j >= 0 && j < N_) {
                kf = *(const float4*)(qkv + base + (size_t)j * QKVW + 512 + sl * 4);
                vf = *(const float4*)(qkv + base + (size_t)j * QKVW + 1024 + sl * 4);
            }
            *(float4*)&k_s[r][((sl ^ (r >> 2)) & 15) * 4] = kf;
            *(float4*)&v_s[r][sl * 4] = vf;
        }
        __syncthreads();

        float s[4][4] = {};
        #pragma unroll 4
        for (int d4 = 0; d4 < 16; ++d4) {
            const int ksl = ((d4 ^ tx) & 15) * 4;
            float4 qa[4], kb[4];
            #pragma unroll
            for (int i = 0; i < 4; ++i) qa[i] = *(const float4*)&q_s[m0 + i][d4 * 4];
            #pragma unroll
            for (int j = 0; j < 4; ++j) kb[j] = *(const float4*)&k_s[n0 + j][ksl];
            #pragma unroll
            for (int i = 0; i < 4; ++i)
                #pragma unroll
                for (int j = 0; j < 4; ++j)
                    s[i][j] += qa[i].x * kb[j].x + qa[i].y * kb[j].y
                             + qa[i].z * kb[j].z + qa[i].w * kb[j].w;
        }

        #pragma unroll
        for (int i = 0; i < 4; ++i) {
            const int gm = i0 + m0 + i;
            bool val[4];
            float mx = -1e30f;
            #pragma unroll
            for (int j = 0; j < 4; ++j) {
                const int gj = jbase + n0 + j;
                const int d  = gj - gm;
                val[j] = (gj >= 0) && (gj < N_) && (d >= -BAND_) && (d < BAND_);
                s[i][j] = val[j] ? s[i][j] : -1e30f;
                mx = fmaxf(mx, s[i][j]);
            }
            #pragma unroll
            for (int o = 1; o < 16; o <<= 1) mx = fmaxf(mx, __shfl_xor(mx, o));
            const float m_new = fmaxf(m_run[i], mx);
            const float alpha = __expf(m_run[i] - m_new);
            float p[4], l_c = 0.f;
            #pragma unroll
            for (int j = 0; j < 4; ++j) {
                p[j] = val[j] ? __expf(s[i][j] - m_new) : 0.0f;
                l_c += p[j];
            }
            #pragma unroll
            for (int o = 1; o < 16; o <<= 1) l_c += __shfl_xor(l_c, o);
            l_run[i] = l_run[i] * alpha + l_c;
            m_run[i] = m_new;
            #pragma unroll
            for (int j = 0; j < 4; ++j) oacc[i][j] *= alpha;
            ushort4 pu;
            pu.x = f2bf(p[0]); pu.y = f2bf(p[1]); pu.z = f2bf(p[2]); pu.w = f2bf(p[3]);
            *(ushort4*)&p_s[m0 + i][n0] = pu;
        }
        __syncthreads();

        #pragma unroll 4
        for (int k4 = 0; k4 < 16; ++k4) {
            float4 vb[4];
            #pragma unroll
            for (int t = 0; t < 4; ++t) vb[t] = *(const float4*)&v_s[k4 * 4 + t][n0];
            #pragma unroll
            for (int i = 0; i < 4; ++i) {
                const ushort4 pu = *(const ushort4*)&p_s[m0 + i][k4 * 4];
                const float pf[4] = { bf2f(pu.x), bf2f(pu.y), bf2f(pu.z), bf2f(pu.w) };
                #pragma unroll
                for (int t = 0; t < 4; ++t) {
                    oacc[i][0] += pf[t] * vb[t].x;
                    oacc[i][1] += pf[t] * vb[t].y;
                    oacc[i][2] += pf[t] * vb[t].z;
                    oacc[i][3] += pf[t] * vb[t].w;
                }
            }
        }
    }

    #pragma unroll
    for (int i = 0; i < 4; ++i) {
        const float inv = 1.0f / l_run[i];
        float4 o = make_float4(oacc[i][0] * inv, oacc[i][1] * inv,
                               oacc[i][2] * inv, oacc[i][3] * inv);
        *(float4*)(out + ((size_t)b * N_ + i0 + m0 + i) * DIM_ + h * DH_ + n0) = o;
    }
}

extern "C" void kernel_launch(void* const* d_in, const int* in_sizes, int n_in,
                              void* d_out, int out_size, void* d_ws, size_t ws_size,
                              hipStream_t stream) {
    const float* x     = (const float*)d_in[0];
    const float* w     = (const float*)d_in[1];
    const float* gamma = (const float*)d_in[2];
    const float* beta  = (const float*)d_in[3];
    float* out = (float*)d_out;

    unsigned short* xnh = (unsigned short*)d_ws;                 // 4096*512  bf16 = 4 MB
    unsigned short* xnl = xnh + (size_t)B_ * N_ * DIM_;          // 4 MB
    unsigned short* wth = xnl + (size_t)B_ * N_ * DIM_;          // 1536*512 bf16 = 1.5 MB
    unsigned short* wtl = wth + (size_t)QKVW * DIM_;             // 1.5 MB
    float*          qkvf = (float*)(wtl + (size_t)QKVW * DIM_);  // 4096*1536 f32 = 25 MB

    ln_kernel<<<dim3(B_ * N_), dim3(256), 0, stream>>>(x, gamma, beta, xnh, xnl);
    wsplit_kernel<<<dim3(QKVW / 64, DIM_ / 64), dim3(256), 0, stream>>>(w, wth, wtl);
    gemm_mfma<<<dim3(QKVW / 128, (B_ * N_) / 128), dim3(256), 0, stream>>>(xnh, xnl, wth, wtl, qkvf);
    attn_kernel<<<dim3(N_ / 64, H_, B_), dim3(256), 0, stream>>>(qkvf, out);
}

// Round 6
// 67.835 us; speedup vs baseline: 4.9165x; 1.5347x over previous
//
#include <hip/hip_runtime.h>
#include <hip/hip_bf16.h>

#define B_    2
#define N_    2048
#define DIM_  512
#define H_    8
#define DH_   64
#define QKVW  1536          // 3*H*DH
#define BAND_ 128
#define LN_EPS 1e-5f

typedef __attribute__((ext_vector_type(8))) short bf16x8;
typedef __attribute__((ext_vector_type(4))) float f32x4;
typedef __attribute__((ext_vector_type(8))) unsigned short ushort8;

__device__ __forceinline__ float bf2f(unsigned short u) {
    union { unsigned int i; float f; } w; w.i = ((unsigned int)u) << 16; return w.f;
}
__device__ __forceinline__ unsigned short f2bf(float f) {
    __hip_bfloat16 h = __float2bfloat16(f);
    return *reinterpret_cast<unsigned short*>(&h);
}

// ---------------- Kernel 1: LayerNorm -> split bf16 (hi, lo) ----------------
__global__ __launch_bounds__(256) void ln_kernel(const float* __restrict__ x,
                                                 const float* __restrict__ gamma,
                                                 const float* __restrict__ beta,
                                                 unsigned short* __restrict__ xh,
                                                 unsigned short* __restrict__ xl) {
    const int row = blockIdx.x;
    const int tid = threadIdx.x;
    const float* xr = x + (size_t)row * DIM_;
    float2 v = *(const float2*)(xr + tid * 2);
    float s  = v.x + v.y;
    float sq = v.x * v.x + v.y * v.y;
    #pragma unroll
    for (int o = 32; o; o >>= 1) { s += __shfl_xor(s, o); sq += __shfl_xor(sq, o); }
    __shared__ float ss[4], ssq[4];
    const int wave = tid >> 6, lane = tid & 63;
    if (lane == 0) { ss[wave] = s; ssq[wave] = sq; }
    __syncthreads();
    s  = ss[0] + ss[1] + ss[2] + ss[3];
    sq = ssq[0] + ssq[1] + ssq[2] + ssq[3];
    const float mu  = s * (1.0f / DIM_);
    const float var = sq * (1.0f / DIM_) - mu * mu;
    const float rs  = rsqrtf(var + LN_EPS);
    float2 g = *(const float2*)(gamma + tid * 2);
    float2 b = *(const float2*)(beta  + tid * 2);
    float y0 = (v.x - mu) * rs * g.x + b.x;
    float y1 = (v.y - mu) * rs * g.y + b.y;
    ushort2 h, l;
    h.x = f2bf(y0); l.x = f2bf(y0 - bf2f(h.x));
    h.y = f2bf(y1); l.y = f2bf(y1 - bf2f(h.y));
    *(ushort2*)(xh + (size_t)row * DIM_ + tid * 2) = h;
    *(ushort2*)(xl + (size_t)row * DIM_ + tid * 2) = l;
}

// ---------------- Kernel 1b: W [512][1536] -> W^T split bf16 [1536][512] ----------------
__global__ __launch_bounds__(256) void wsplit_kernel(const float* __restrict__ W,
                                                     unsigned short* __restrict__ Bh,
                                                     unsigned short* __restrict__ Bl) {
    __shared__ float T[64][65];
    const int n0 = blockIdx.x * 64, k0 = blockIdx.y * 64;
    const int tid = threadIdx.x;
    #pragma unroll
    for (int e = 0; e < 4; ++e) {
        const int lin = e * 256 + tid;       // 0..1023
        const int kk = lin >> 4;             // 0..63
        const int n4 = (lin & 15) * 4;
        float4 f = *(const float4*)(W + (size_t)(k0 + kk) * QKVW + n0 + n4);
        T[kk][n4 + 0] = f.x; T[kk][n4 + 1] = f.y;
        T[kk][n4 + 2] = f.z; T[kk][n4 + 3] = f.w;
    }
    __syncthreads();
    #pragma unroll
    for (int e = 0; e < 4; ++e) {
        const int lin = e * 256 + tid;
        const int nn = lin >> 4;             // 0..63
        const int kq = (lin & 15) * 4;       // 0..60
        ushort4 h, l;
        float f;
        f = T[kq + 0][nn]; h.x = f2bf(f); l.x = f2bf(f - bf2f(h.x));
        f = T[kq + 1][nn]; h.y = f2bf(f); l.y = f2bf(f - bf2f(h.y));
        f = T[kq + 2][nn]; h.z = f2bf(f); l.z = f2bf(f - bf2f(h.z));
        f = T[kq + 3][nn]; h.w = f2bf(f); l.w = f2bf(f - bf2f(h.w));
        *(ushort4*)(Bh + (size_t)(n0 + nn) * DIM_ + k0 + kq) = h;
        *(ushort4*)(Bl + (size_t)(n0 + nn) * DIM_ + k0 + kq) = l;
    }
}

// ---------------- Kernel 2: MFMA GEMM, 3-pass split-bf16 (unchanged, verified) ----------------
__global__ __launch_bounds__(256) void gemm_mfma(const unsigned short* __restrict__ Ah,
                                                 const unsigned short* __restrict__ Al,
                                                 const unsigned short* __restrict__ Bh,
                                                 const unsigned short* __restrict__ Bl,
                                                 float* __restrict__ C) {
    __shared__ unsigned short sAh[128 * 32], sAl[128 * 32];
    __shared__ unsigned short sBh[128 * 32], sBl[128 * 32];
    const int tid  = threadIdx.x;
    const int lane = tid & 63, wave = tid >> 6;
    const int wr = wave >> 1, wc = wave & 1;
    const int row0 = blockIdx.y * 128;
    const int col0 = blockIdx.x * 128;

    f32x4 acc[4][4] = {};

    for (int k0 = 0; k0 < DIM_; k0 += 32) {
        __syncthreads();
        #pragma unroll
        for (int e = 0; e < 2; ++e) {
            const int idx = e * 256 + tid;       // 0..511
            const int r   = idx >> 2;            // 0..127
            const int k8  = (idx & 3) * 8;       // 0,8,16,24
            const int sidx = r * 32 + k8;
            *(ushort8*)&sAh[sidx] = *(const ushort8*)(Ah + (size_t)(row0 + r) * DIM_ + k0 + k8);
            *(ushort8*)&sAl[sidx] = *(const ushort8*)(Al + (size_t)(row0 + r) * DIM_ + k0 + k8);
            *(ushort8*)&sBh[sidx] = *(const ushort8*)(Bh + (size_t)(col0 + r) * DIM_ + k0 + k8);
            *(ushort8*)&sBl[sidx] = *(const ushort8*)(Bl + (size_t)(col0 + r) * DIM_ + k0 + k8);
        }
        __syncthreads();

        const int kb = (lane >> 4) * 8;
        bf16x8 ah[4], al[4], bh[4], bl[4];
        #pragma unroll
        for (int mi = 0; mi < 4; ++mi) {
            const int r = wr * 64 + mi * 16 + (lane & 15);
            ah[mi] = *(const bf16x8*)&sAh[r * 32 + kb];
            al[mi] = *(const bf16x8*)&sAl[r * 32 + kb];
        }
        #pragma unroll
        for (int ni = 0; ni < 4; ++ni) {
            const int r = wc * 64 + ni * 16 + (lane & 15);
            bh[ni] = *(const bf16x8*)&sBh[r * 32 + kb];
            bl[ni] = *(const bf16x8*)&sBl[r * 32 + kb];
        }
        #pragma unroll
        for (int mi = 0; mi < 4; ++mi)
            #pragma unroll
            for (int ni = 0; ni < 4; ++ni) {
                acc[mi][ni] = __builtin_amdgcn_mfma_f32_16x16x32_bf16(ah[mi], bh[ni], acc[mi][ni], 0, 0, 0);
                acc[mi][ni] = __builtin_amdgcn_mfma_f32_16x16x32_bf16(al[mi], bh[ni], acc[mi][ni], 0, 0, 0);
                acc[mi][ni] = __builtin_amdgcn_mfma_f32_16x16x32_bf16(ah[mi], bl[ni], acc[mi][ni], 0, 0, 0);
            }
    }

    #pragma unroll
    for (int mi = 0; mi < 4; ++mi)
        #pragma unroll
        for (int ni = 0; ni < 4; ++ni) {
            const int col   = col0 + wc * 64 + ni * 16 + (lane & 15);
            const int rbase = row0 + wr * 64 + mi * 16 + (lane >> 4) * 4;
            #pragma unroll
            for (int r = 0; r < 4; ++r)
                C[(size_t)(rbase + r) * QKVW + col] = acc[mi][ni][r];
        }
}

// ---------------- Kernel 3: banded attention, MFMA ----------------
// block = 256 (4 waves) per (b, h, 64-query tile). Wave owns 16 q-rows.
// Q,K split-bf16 (3-pass QK^T); P,V single bf16. All LDS tiles [64][64] bf16
// with 16B-block XOR swizzle: phys_block = (k>>3) ^ (row&7).
__global__ __launch_bounds__(256) void attn_mfma(const float* __restrict__ qkv,
                                                 float* __restrict__ out) {
    const int tile = blockIdx.x, h = blockIdx.y, b = blockIdx.z;
    const int i0   = tile * 64;
    const int tid  = threadIdx.x;
    const int lane = tid & 63, wave = tid >> 6;
    const int lg   = lane >> 4, l16 = lane & 15;

    __shared__ unsigned short sQh[64 * 64], sQl[64 * 64];
    __shared__ unsigned short sKh[64 * 64], sKl[64 * 64];
    __shared__ unsigned short sVt[64 * 64];          // [d][key], swizzled
    __shared__ unsigned short sP[4][16 * 64];        // per-wave [q][key], swizzled

    const size_t base = ((size_t)b * N_) * QKVW + (size_t)h * DH_;

    // ---- stage Q (split bf16, swizzled): 512 ushort8 blocks, 2/thread ----
    #pragma unroll
    for (int e = 0; e < 2; ++e) {
        const int bi = e * 256 + tid;
        const int r = bi >> 3, k8 = bi & 7;
        const float* src = qkv + base + (size_t)(i0 + r) * QKVW + k8 * 8;
        float4 f0 = *(const float4*)(src);
        float4 f1 = *(const float4*)(src + 4);
        const float fv[8] = { f0.x, f0.y, f0.z, f0.w, f1.x, f1.y, f1.z, f1.w };
        ushort8 uh, ul;
        #pragma unroll
        for (int j = 0; j < 8; ++j) {
            const unsigned short hv = f2bf(fv[j]);
            uh[j] = hv; ul[j] = f2bf(fv[j] - bf2f(hv));
        }
        const int off = r * 64 + ((k8 ^ (r & 7)) * 8);
        *(ushort8*)&sQh[off] = uh;
        *(ushort8*)&sQl[off] = ul;
    }
    __syncthreads();

    // persistent Q A-frags: row = wave*16 + l16, k = kh*32 + lg*8
    bf16x8 qh[2], ql[2];
    #pragma unroll
    for (int kh = 0; kh < 2; ++kh) {
        const int r = wave * 16 + l16;
        const int off = r * 64 + ((((kh * 4 + lg)) ^ (r & 7)) * 8);
        qh[kh] = *(const bf16x8*)&sQh[off];
        ql[kh] = *(const bf16x8*)&sQl[off];
    }

    float m_run[4], l_run[4];
    f32x4 oacc[4] = {};                  // oacc[dtile][reg]
    #pragma unroll
    for (int r = 0; r < 4; ++r) { m_run[r] = -1e30f; l_run[r] = 0.0f; }

    #pragma unroll 1
    for (int c = 0; c < 5; ++c) {
        const int jbase = i0 - 128 + c * 64;
        if (jbase + 64 <= 0 || jbase >= N_) continue;   // uniform per block
        __syncthreads();
        // ---- stage K (split) + V^T for keys [jbase, jbase+64) ----
        #pragma unroll
        for (int e = 0; e < 2; ++e) {
            const int bi = e * 256 + tid;
            const int r = bi >> 3, k8 = bi & 7;   // r = key row, k8 = d-block
            const int j = jbase + r;
            float fv[8] = {0.f,0.f,0.f,0.f,0.f,0.f,0.f,0.f};
            float vv[8] = {0.f,0.f,0.f,0.f,0.f,0.f,0.f,0.f};
            if (j >= 0 && j < N_) {
                const float* sk = qkv + base + (size_t)j * QKVW + 512 + k8 * 8;
                const float* sv = qkv + base + (size_t)j * QKVW + 1024 + k8 * 8;
                float4 a0 = *(const float4*)(sk), a1 = *(const float4*)(sk + 4);
                float4 b0 = *(const float4*)(sv), b1 = *(const float4*)(sv + 4);
                fv[0]=a0.x; fv[1]=a0.y; fv[2]=a0.z; fv[3]=a0.w;
                fv[4]=a1.x; fv[5]=a1.y; fv[6]=a1.z; fv[7]=a1.w;
                vv[0]=b0.x; vv[1]=b0.y; vv[2]=b0.z; vv[3]=b0.w;
                vv[4]=b1.x; vv[5]=b1.y; vv[6]=b1.z; vv[7]=b1.w;
            }
            ushort8 uh, ul;
            #pragma unroll
            for (int t = 0; t < 8; ++t) {
                const unsigned short hv = f2bf(fv[t]);
                uh[t] = hv; ul[t] = f2bf(fv[t] - bf2f(hv));
            }
            const int off = r * 64 + ((k8 ^ (r & 7)) * 8);
            *(ushort8*)&sKh[off] = uh;
            *(ushort8*)&sKl[off] = ul;
            // V transposed: sVt[d8+t][key r], phys block = (r>>3) ^ t
            const int d8 = k8 * 8;
            #pragma unroll
            for (int t = 0; t < 8; ++t)
                sVt[(d8 + t) * 64 + (((r >> 3) ^ t) * 8) + (r & 7)] = f2bf(vv[t]);
        }
        __syncthreads();

        // ---- S = Q K^T (3-pass split), wave: 16 q-rows x 64 keys ----
        f32x4 sacc[4] = {};
        #pragma unroll
        for (int kh = 0; kh < 2; ++kh) {
            #pragma unroll
            for (int t = 0; t < 4; ++t) {
                const int r = t * 16 + l16;
                const int off = r * 64 + ((((kh * 4 + lg)) ^ (r & 7)) * 8);
                const bf16x8 kbh = *(const bf16x8*)&sKh[off];
                const bf16x8 kbl = *(const bf16x8*)&sKl[off];
                sacc[t] = __builtin_amdgcn_mfma_f32_16x16x32_bf16(qh[kh], kbh, sacc[t], 0, 0, 0);
                sacc[t] = __builtin_amdgcn_mfma_f32_16x16x32_bf16(ql[kh], kbh, sacc[t], 0, 0, 0);
                sacc[t] = __builtin_amdgcn_mfma_f32_16x16x32_bf16(qh[kh], kbl, sacc[t], 0, 0, 0);
            }
        }

        // ---- online softmax; P -> per-wave LDS (bf16, swizzled) ----
        #pragma unroll
        for (int r = 0; r < 4; ++r) {
            const int i = i0 + wave * 16 + lg * 4 + r;
            float sv[4];
            float mx = -1e30f;
            #pragma unroll
            for (int t = 0; t < 4; ++t) {
                const int j = jbase + t * 16 + l16;
                const int d = j - i;
                const bool ok = (j >= 0) && (j < N_) && (d >= -BAND_) && (d < BAND_);
                sv[t] = ok ? sacc[t][r] : -1e30f;
                mx = fmaxf(mx, sv[t]);
            }
            #pragma unroll
            for (int o = 1; o < 16; o <<= 1) mx = fmaxf(mx, __shfl_xor(mx, o));
            const float m_new = fmaxf(m_run[r], mx);
            const float alpha = __expf(m_run[r] - m_new);
            float p[4], lc = 0.f;
            #pragma unroll
            for (int t = 0; t < 4; ++t) { p[t] = __expf(sv[t] - m_new); lc += p[t]; }
            #pragma unroll
            for (int o = 1; o < 16; o <<= 1) lc += __shfl_xor(lc, o);
            l_run[r] = l_run[r] * alpha + lc;
            m_run[r] = m_new;
            #pragma unroll
            for (int dt = 0; dt < 4; ++dt) oacc[dt][r] *= alpha;
            const int q = lg * 4 + r;
            #pragma unroll
            for (int t = 0; t < 4; ++t) {
                const int k = t * 16 + l16;
                sP[wave][q * 64 + (((k >> 3) ^ (q & 7)) * 8) + (k & 7)] = f2bf(p[t]);
            }
        }

        // ---- O += P V ----
        #pragma unroll
        for (int kh = 0; kh < 2; ++kh) {
            const int poff = l16 * 64 + ((((kh * 4 + lg)) ^ (l16 & 7)) * 8);
            const bf16x8 pa = *(const bf16x8*)&sP[wave][poff];
            #pragma unroll
            for (int dt = 0; dt < 4; ++dt) {
                const int rv = dt * 16 + l16;
                const int voff = rv * 64 + ((((kh * 4 + lg)) ^ (rv & 7)) * 8);
                const bf16x8 vb = *(const bf16x8*)&sVt[voff];
                oacc[dt] = __builtin_amdgcn_mfma_f32_16x16x32_bf16(pa, vb, oacc[dt], 0, 0, 0);
            }
        }
    }

    // ---- epilogue ----
    #pragma unroll
    for (int dt = 0; dt < 4; ++dt)
        #pragma unroll
        for (int r = 0; r < 4; ++r) {
            const int i = i0 + wave * 16 + lg * 4 + r;
            out[((size_t)b * N_ + i) * DIM_ + h * DH_ + dt * 16 + l16] = oacc[dt][r] / l_run[r];
        }
}

extern "C" void kernel_launch(void* const* d_in, const int* in_sizes, int n_in,
                              void* d_out, int out_size, void* d_ws, size_t ws_size,
                              hipStream_t stream) {
    const float* x     = (const float*)d_in[0];
    const float* w     = (const float*)d_in[1];
    const float* gamma = (const float*)d_in[2];
    const float* beta  = (const float*)d_in[3];
    float* out = (float*)d_out;

    unsigned short* xnh = (unsigned short*)d_ws;                 // 4 MB
    unsigned short* xnl = xnh + (size_t)B_ * N_ * DIM_;          // 4 MB
    unsigned short* wth = xnl + (size_t)B_ * N_ * DIM_;          // 1.5 MB
    unsigned short* wtl = wth + (size_t)QKVW * DIM_;             // 1.5 MB
    float*          qkvf = (float*)(wtl + (size_t)QKVW * DIM_);  // 25 MB

    ln_kernel<<<dim3(B_ * N_), dim3(256), 0, stream>>>(x, gamma, beta, xnh, xnl);
    wsplit_kernel<<<dim3(QKVW / 64, DIM_ / 64), dim3(256), 0, stream>>>(w, wth, wtl);
    gemm_mfma<<<dim3(QKVW / 128, (B_ * N_) / 128), dim3(256), 0, stream>>>(xnh, xnl, wth, wtl, qkvf);
    attn_mfma<<<dim3(N_ / 64, H_, B_), dim3(256), 0, stream>>>(qkvf, out);
}

// Round 7
// 63.995 us; speedup vs baseline: 5.2115x; 1.0600x over previous
//
#include <hip/hip_runtime.h>
#include <hip/hip_bf16.h>

#define B_    2
#define N_    2048
#define DIM_  512
#define H_    8
#define DH_   64
#define QKVW  1536          // 3*H*DH
#define BAND_ 128
#define LN_EPS 1e-5f

typedef __attribute__((ext_vector_type(8))) short bf16x8;
typedef __attribute__((ext_vector_type(4))) float f32x4;
typedef __attribute__((ext_vector_type(8))) unsigned short ushort8;

__device__ __forceinline__ float bf2f(unsigned short u) {
    union { unsigned int i; float f; } w; w.i = ((unsigned int)u) << 16; return w.f;
}
__device__ __forceinline__ unsigned short f2bf(float f) {
    __hip_bfloat16 h = __float2bfloat16(f);
    return *reinterpret_cast<unsigned short*>(&h);
}

// ---------------- Kernel 1: LayerNorm -> split bf16 (hi, lo) ----------------
__global__ __launch_bounds__(256) void ln_kernel(const float* __restrict__ x,
                                                 const float* __restrict__ gamma,
                                                 const float* __restrict__ beta,
                                                 unsigned short* __restrict__ xh,
                                                 unsigned short* __restrict__ xl) {
    const int row = blockIdx.x;
    const int tid = threadIdx.x;
    const float* xr = x + (size_t)row * DIM_;
    float2 v = *(const float2*)(xr + tid * 2);
    float s  = v.x + v.y;
    float sq = v.x * v.x + v.y * v.y;
    #pragma unroll
    for (int o = 32; o; o >>= 1) { s += __shfl_xor(s, o); sq += __shfl_xor(sq, o); }
    __shared__ float ss[4], ssq[4];
    const int wave = tid >> 6, lane = tid & 63;
    if (lane == 0) { ss[wave] = s; ssq[wave] = sq; }
    __syncthreads();
    s  = ss[0] + ss[1] + ss[2] + ss[3];
    sq = ssq[0] + ssq[1] + ssq[2] + ssq[3];
    const float mu  = s * (1.0f / DIM_);
    const float var = sq * (1.0f / DIM_) - mu * mu;
    const float rs  = rsqrtf(var + LN_EPS);
    float2 g = *(const float2*)(gamma + tid * 2);
    float2 b = *(const float2*)(beta  + tid * 2);
    float y0 = (v.x - mu) * rs * g.x + b.x;
    float y1 = (v.y - mu) * rs * g.y + b.y;
    ushort2 h, l;
    h.x = f2bf(y0); l.x = f2bf(y0 - bf2f(h.x));
    h.y = f2bf(y1); l.y = f2bf(y1 - bf2f(h.y));
    *(ushort2*)(xh + (size_t)row * DIM_ + tid * 2) = h;
    *(ushort2*)(xl + (size_t)row * DIM_ + tid * 2) = l;
}

// ---------------- Kernel 1b: W [512][1536] -> W^T split bf16 [1536][512] ----------------
__global__ __launch_bounds__(256) void wsplit_kernel(const float* __restrict__ W,
                                                     unsigned short* __restrict__ Bh,
                                                     unsigned short* __restrict__ Bl) {
    __shared__ float T[64][65];
    const int n0 = blockIdx.x * 64, k0 = blockIdx.y * 64;
    const int tid = threadIdx.x;
    #pragma unroll
    for (int e = 0; e < 4; ++e) {
        const int lin = e * 256 + tid;       // 0..1023
        const int kk = lin >> 4;             // 0..63
        const int n4 = (lin & 15) * 4;
        float4 f = *(const float4*)(W + (size_t)(k0 + kk) * QKVW + n0 + n4);
        T[kk][n4 + 0] = f.x; T[kk][n4 + 1] = f.y;
        T[kk][n4 + 2] = f.z; T[kk][n4 + 3] = f.w;
    }
    __syncthreads();
    #pragma unroll
    for (int e = 0; e < 4; ++e) {
        const int lin = e * 256 + tid;
        const int nn = lin >> 4;             // 0..63
        const int kq = (lin & 15) * 4;       // 0..60
        ushort4 h, l;
        float f;
        f = T[kq + 0][nn]; h.x = f2bf(f); l.x = f2bf(f - bf2f(h.x));
        f = T[kq + 1][nn]; h.y = f2bf(f); l.y = f2bf(f - bf2f(h.y));
        f = T[kq + 2][nn]; h.z = f2bf(f); l.z = f2bf(f - bf2f(h.z));
        f = T[kq + 3][nn]; h.w = f2bf(f); l.w = f2bf(f - bf2f(h.w));
        *(ushort4*)(Bh + (size_t)(n0 + nn) * DIM_ + k0 + kq) = h;
        *(ushort4*)(Bl + (size_t)(n0 + nn) * DIM_ + k0 + kq) = l;
    }
}

// ---------------- Kernel 2: MFMA GEMM, 3-pass split-bf16, fused repack epilogue ----
// Writes per-head 64x64 swizzled tile images consumed by attn:
//   Qh/Ql, Kh/Kl: [(b*H+head)*32 + tile][r][ (k8^(r&7))*8 + (d&7) ]   (r=n&63, k8=d>>3)
//   Vt          : [(b*H+head)*32 + chunk][d][ ((nr>>3)^(d&7))*8 + (nr&7) ] (nr=n&63)
__global__ __launch_bounds__(256) void gemm_mfma(const unsigned short* __restrict__ Ah,
                                                 const unsigned short* __restrict__ Al,
                                                 const unsigned short* __restrict__ Bh,
                                                 const unsigned short* __restrict__ Bl,
                                                 unsigned short* __restrict__ Qh,
                                                 unsigned short* __restrict__ Ql,
                                                 unsigned short* __restrict__ Kh,
                                                 unsigned short* __restrict__ Kl,
                                                 unsigned short* __restrict__ Vt) {
    __shared__ unsigned short sAh[128 * 32], sAl[128 * 32];
    __shared__ unsigned short sBh[128 * 32], sBl[128 * 32];
    const int tid  = threadIdx.x;
    const int lane = tid & 63, wave = tid >> 6;
    const int wr = wave >> 1, wc = wave & 1;
    const int lg = lane >> 4, l16 = lane & 15;
    const int row0 = blockIdx.y * 128;
    const int col0 = blockIdx.x * 128;

    f32x4 acc[4][4] = {};

    for (int k0 = 0; k0 < DIM_; k0 += 32) {
        __syncthreads();
        #pragma unroll
        for (int e = 0; e < 2; ++e) {
            const int idx = e * 256 + tid;       // 0..511
            const int r   = idx >> 2;            // 0..127
            const int k8  = (idx & 3) * 8;       // 0,8,16,24
            const int sidx = r * 32 + k8;
            *(ushort8*)&sAh[sidx] = *(const ushort8*)(Ah + (size_t)(row0 + r) * DIM_ + k0 + k8);
            *(ushort8*)&sAl[sidx] = *(const ushort8*)(Al + (size_t)(row0 + r) * DIM_ + k0 + k8);
            *(ushort8*)&sBh[sidx] = *(const ushort8*)(Bh + (size_t)(col0 + r) * DIM_ + k0 + k8);
            *(ushort8*)&sBl[sidx] = *(const ushort8*)(Bl + (size_t)(col0 + r) * DIM_ + k0 + k8);
        }
        __syncthreads();

        const int kb = lg * 8;
        bf16x8 ah[4], al[4], bh[4], bl[4];
        #pragma unroll
        for (int mi = 0; mi < 4; ++mi) {
            const int r = wr * 64 + mi * 16 + l16;
            ah[mi] = *(const bf16x8*)&sAh[r * 32 + kb];
            al[mi] = *(const bf16x8*)&sAl[r * 32 + kb];
        }
        #pragma unroll
        for (int ni = 0; ni < 4; ++ni) {
            const int r = wc * 64 + ni * 16 + l16;
            bh[ni] = *(const bf16x8*)&sBh[r * 32 + kb];
            bl[ni] = *(const bf16x8*)&sBl[r * 32 + kb];
        }
        #pragma unroll
        for (int mi = 0; mi < 4; ++mi)
            #pragma unroll
            for (int ni = 0; ni < 4; ++ni) {
                acc[mi][ni] = __builtin_amdgcn_mfma_f32_16x16x32_bf16(ah[mi], bh[ni], acc[mi][ni], 0, 0, 0);
                acc[mi][ni] = __builtin_amdgcn_mfma_f32_16x16x32_bf16(al[mi], bh[ni], acc[mi][ni], 0, 0, 0);
                acc[mi][ni] = __builtin_amdgcn_mfma_f32_16x16x32_bf16(ah[mi], bl[ni], acc[mi][ni], 0, 0, 0);
            }
    }

    // ---- fused repack epilogue (C/D layout: col = l16, row = lg*4 + rr [m89]) ----
    const int colbase = col0 + wc * 64;          // multiple of 64
    const int part = colbase >> 9;               // 0=Q, 1=K, 2=V (wave-uniform)
    const int head = (colbase & 511) >> 6;       // wave-uniform
    if (part < 2) {
        unsigned short* __restrict__ Ih = (part == 0) ? Qh : Kh;
        unsigned short* __restrict__ Il = (part == 0) ? Ql : Kl;
        #pragma unroll
        for (int mi = 0; mi < 4; ++mi) {
            const int rb = row0 + wr * 64 + mi * 16 + lg * 4;   // token row base
            const int n  = rb & 2047;
            const size_t tbase = ((size_t)((rb >> 11) * H_ + head) * 32 + (n >> 6)) * 4096;
            #pragma unroll
            for (int ni = 0; ni < 4; ++ni) {
                const int d  = ni * 16 + l16;
                const int k8 = d >> 3;
                #pragma unroll
                for (int rr = 0; rr < 4; ++rr) {
                    const int r = (n & 63) + rr;
                    const size_t off = tbase + r * 64 + ((k8 ^ (r & 7)) * 8) + (d & 7);
                    const float v = acc[mi][ni][rr];
                    const unsigned short hv = f2bf(v);
                    Ih[off] = hv;
                    Il[off] = f2bf(v - bf2f(hv));
                }
            }
        }
    } else {
        #pragma unroll
        for (int mi = 0; mi < 4; ++mi) {
            const int rb = row0 + wr * 64 + mi * 16 + lg * 4;
            const int n  = rb & 2047;
            const size_t cbase = ((size_t)((rb >> 11) * H_ + head) * 32 + (n >> 6)) * 4096;
            const int nr = n & 63;
            #pragma unroll
            for (int ni = 0; ni < 4; ++ni) {
                const int d = ni * 16 + l16;
                const size_t off = cbase + d * 64 + (((nr >> 3) ^ (d & 7)) * 8) + (nr & 7);
                ushort4 pk;
                pk.x = f2bf(acc[mi][ni][0]); pk.y = f2bf(acc[mi][ni][1]);
                pk.z = f2bf(acc[mi][ni][2]); pk.w = f2bf(acc[mi][ni][3]);
                *(ushort4*)&Vt[off] = pk;
            }
        }
    }
}

// ---------------- Kernel 3: banded attention, MFMA, image-fed ----------------
// block = 256 (4 waves) per (b, h, 64-query tile). Wave owns 16 q-rows.
// Q,K split-bf16 (3-pass QK^T); P,V single bf16. Staging = raw bf16 copies.
__global__ __launch_bounds__(256) void attn_mfma(const unsigned short* __restrict__ Qh,
                                                 const unsigned short* __restrict__ Ql,
                                                 const unsigned short* __restrict__ Kh,
                                                 const unsigned short* __restrict__ Kl,
                                                 const unsigned short* __restrict__ Vt,
                                                 float* __restrict__ out) {
    const int tile = blockIdx.x, h = blockIdx.y, b = blockIdx.z;
    const int i0   = tile * 64;
    const int tid  = threadIdx.x;
    const int lane = tid & 63, wave = tid >> 6;
    const int lg   = lane >> 4, l16 = lane & 15;

    __shared__ unsigned short sKh[4096], sKl[4096], sVt[4096];
    __shared__ unsigned short sP[4][1024];

    const size_t hb = (size_t)(b * H_ + h) * 32;

    // ---- Q fragments straight from the swizzled tile image ----
    bf16x8 qh[2], ql[2];
    {
        const int r = wave * 16 + l16;
        const size_t tb = (hb + tile) * 4096;
        #pragma unroll
        for (int kh = 0; kh < 2; ++kh) {
            const size_t off = tb + r * 64 + (((kh * 4 + lg) ^ (r & 7)) * 8);
            qh[kh] = *(const bf16x8*)(Qh + off);
            ql[kh] = *(const bf16x8*)(Ql + off);
        }
    }

    float m_run[4], l_run[4];
    f32x4 oacc[4] = {};                  // oacc[dtile][reg]
    #pragma unroll
    for (int r = 0; r < 4; ++r) { m_run[r] = -1e30f; l_run[r] = 0.0f; }

    #pragma unroll 1
    for (int c = 0; c < 5; ++c) {
        const int jbase = i0 - 128 + c * 64;
        if (jbase + 64 <= 0 || jbase >= N_) continue;   // staged chunks fully in-bounds
        __syncthreads();
        // ---- stage K (split) + V^T: raw bf16 copies of pre-swizzled images ----
        const size_t kb = (hb + (jbase >> 6)) * 4096;
        #pragma unroll
        for (int e = 0; e < 6; ++e) {
            const int s = e * 256 + tid;          // 0..1535
            const int arr = s >> 9;               // wave-uniform
            const int w = (s & 511) * 8;
            if (arr == 0)      *(ushort8*)&sKh[w] = *(const ushort8*)(Kh + kb + w);
            else if (arr == 1) *(ushort8*)&sKl[w] = *(const ushort8*)(Kl + kb + w);
            else               *(ushort8*)&sVt[w] = *(const ushort8*)(Vt + kb + w);
        }
        __syncthreads();

        // ---- S = Q K^T (3-pass split), wave: 16 q-rows x 64 keys ----
        f32x4 sacc[4] = {};
        #pragma unroll
        for (int kh = 0; kh < 2; ++kh) {
            #pragma unroll
            for (int t = 0; t < 4; ++t) {
                const int r = t * 16 + l16;
                const int off = r * 64 + ((((kh * 4 + lg)) ^ (r & 7)) * 8);
                const bf16x8 kbh = *(const bf16x8*)&sKh[off];
                const bf16x8 kbl = *(const bf16x8*)&sKl[off];
                sacc[t] = __builtin_amdgcn_mfma_f32_16x16x32_bf16(qh[kh], kbh, sacc[t], 0, 0, 0);
                sacc[t] = __builtin_amdgcn_mfma_f32_16x16x32_bf16(ql[kh], kbh, sacc[t], 0, 0, 0);
                sacc[t] = __builtin_amdgcn_mfma_f32_16x16x32_bf16(qh[kh], kbl, sacc[t], 0, 0, 0);
            }
        }

        // ---- online softmax; P -> per-wave LDS (bf16, swizzled) ----
        #pragma unroll
        for (int r = 0; r < 4; ++r) {
            const int i = i0 + wave * 16 + lg * 4 + r;
            float sv[4];
            float mx = -1e30f;
            #pragma unroll
            for (int t = 0; t < 4; ++t) {
                const int j = jbase + t * 16 + l16;
                const int d = j - i;
                const bool ok = (d >= -BAND_) && (d < BAND_);
                sv[t] = ok ? sacc[t][r] : -1e30f;
                mx = fmaxf(mx, sv[t]);
            }
            #pragma unroll
            for (int o = 1; o < 16; o <<= 1) mx = fmaxf(mx, __shfl_xor(mx, o));
            const float m_new = fmaxf(m_run[r], mx);
            const float alpha = __expf(m_run[r] - m_new);
            float p[4], lc = 0.f;
            #pragma unroll
            for (int t = 0; t < 4; ++t) { p[t] = __expf(sv[t] - m_new); lc += p[t]; }
            #pragma unroll
            for (int o = 1; o < 16; o <<= 1) lc += __shfl_xor(lc, o);
            l_run[r] = l_run[r] * alpha + lc;
            m_run[r] = m_new;
            #pragma unroll
            for (int dt = 0; dt < 4; ++dt) oacc[dt][r] *= alpha;
            const int q = lg * 4 + r;
            #pragma unroll
            for (int t = 0; t < 4; ++t) {
                const int k = t * 16 + l16;
                sP[wave][q * 64 + (((k >> 3) ^ (q & 7)) * 8) + (k & 7)] = f2bf(p[t]);
            }
        }

        // ---- O += P V ----
        #pragma unroll
        for (int kh = 0; kh < 2; ++kh) {
            const int poff = l16 * 64 + ((((kh * 4 + lg)) ^ (l16 & 7)) * 8);
            const bf16x8 pa = *(const bf16x8*)&sP[wave][poff];
            #pragma unroll
            for (int dt = 0; dt < 4; ++dt) {
                const int rv = dt * 16 + l16;
                const int voff = rv * 64 + ((((kh * 4 + lg)) ^ (rv & 7)) * 8);
                const bf16x8 vb = *(const bf16x8*)&sVt[voff];
                oacc[dt] = __builtin_amdgcn_mfma_f32_16x16x32_bf16(pa, vb, oacc[dt], 0, 0, 0);
            }
        }
    }

    // ---- epilogue ----
    #pragma unroll
    for (int dt = 0; dt < 4; ++dt)
        #pragma unroll
        for (int r = 0; r < 4; ++r) {
            const int i = i0 + wave * 16 + lg * 4 + r;
            out[((size_t)b * N_ + i) * DIM_ + h * DH_ + dt * 16 + l16] = oacc[dt][r] / l_run[r];
        }
}

extern "C" void kernel_launch(void* const* d_in, const int* in_sizes, int n_in,
                              void* d_out, int out_size, void* d_ws, size_t ws_size,
                              hipStream_t stream) {
    const float* x     = (const float*)d_in[0];
    const float* w     = (const float*)d_in[1];
    const float* gamma = (const float*)d_in[2];
    const float* beta  = (const float*)d_in[3];
    float* out = (float*)d_out;

    const size_t NTOK = (size_t)B_ * N_;            // 4096
    const size_t IMG  = (size_t)B_ * H_ * 32 * 4096; // 2,097,152 u16 per image

    unsigned short* xnh = (unsigned short*)d_ws;     // 4 MB
    unsigned short* xnl = xnh + NTOK * DIM_;         // 4 MB
    unsigned short* wth = xnl + NTOK * DIM_;         // 1.5 MB
    unsigned short* wtl = wth + (size_t)QKVW * DIM_; // 1.5 MB
    unsigned short* Qh  = wtl + (size_t)QKVW * DIM_; // 4 MB each below
    unsigned short* Ql  = Qh + IMG;
    unsigned short* Kh  = Ql + IMG;
    unsigned short* Kl  = Kh + IMG;
    unsigned short* Vt  = Kl + IMG;

    ln_kernel<<<dim3(B_ * N_), dim3(256), 0, stream>>>(x, gamma, beta, xnh, xnl);
    wsplit_kernel<<<dim3(QKVW / 64, DIM_ / 64), dim3(256), 0, stream>>>(w, wth, wtl);
    gemm_mfma<<<dim3(QKVW / 128, (B_ * N_) / 128), dim3(256), 0, stream>>>(
        xnh, xnl, wth, wtl, Qh, Ql, Kh, Kl, Vt);
    attn_mfma<<<dim3(N_ / 64, H_, B_), dim3(256), 0, stream>>>(Qh, Ql, Kh, Kl, Vt, out);
}

// Round 8
// 59.355 us; speedup vs baseline: 5.6189x; 1.0782x over previous
//
#include <hip/hip_runtime.h>
#include <hip/hip_bf16.h>

#define B_    2
#define N_    2048
#define DIM_  512
#define H_    8
#define DH_   64
#define QKVW  1536          // 3*H*DH
#define BAND_ 128
#define LN_EPS 1e-5f

typedef __attribute__((ext_vector_type(8))) short bf16x8;
typedef __attribute__((ext_vector_type(4))) float f32x4;
typedef __attribute__((ext_vector_type(8))) unsigned short ushort8;

__device__ __forceinline__ float bf2f(unsigned short u) {
    union { unsigned int i; float f; } w; w.i = ((unsigned int)u) << 16; return w.f;
}
__device__ __forceinline__ unsigned short f2bf(float f) {
    __hip_bfloat16 h = __float2bfloat16(f);
    return *reinterpret_cast<unsigned short*>(&h);
}
// async global->LDS, 16B per lane; lds base must be wave-uniform (HW adds lane*16)
__device__ __forceinline__ void async_copy16(void* lds, const void* g) {
    __builtin_amdgcn_global_load_lds(
        (const __attribute__((address_space(1))) unsigned int*)g,
        (__attribute__((address_space(3))) unsigned int*)lds, 16, 0, 0);
}

// ---------------- Kernel 1: LayerNorm -> split bf16, 1 wave/row ----------------
__global__ __launch_bounds__(256) void ln_kernel(const float* __restrict__ x,
                                                 const float* __restrict__ gamma,
                                                 const float* __restrict__ beta,
                                                 unsigned short* __restrict__ xh,
                                                 unsigned short* __restrict__ xl) {
    const int row  = blockIdx.x * 4 + (threadIdx.x >> 6);
    const int lane = threadIdx.x & 63;
    const float* xr = x + (size_t)row * DIM_ + lane * 8;
    float4 a = *(const float4*)xr;
    float4 c = *(const float4*)(xr + 4);
    float s  = (a.x + a.y) + (a.z + a.w) + (c.x + c.y) + (c.z + c.w);
    float sq = a.x*a.x + a.y*a.y + a.z*a.z + a.w*a.w
             + c.x*c.x + c.y*c.y + c.z*c.z + c.w*c.w;
    #pragma unroll
    for (int o = 32; o; o >>= 1) { s += __shfl_xor(s, o); sq += __shfl_xor(sq, o); }
    const float mu  = s * (1.0f / DIM_);
    const float var = sq * (1.0f / DIM_) - mu * mu;
    const float rs  = rsqrtf(var + LN_EPS);
    float4 g0 = *(const float4*)(gamma + lane * 8);
    float4 g1 = *(const float4*)(gamma + lane * 8 + 4);
    float4 b0 = *(const float4*)(beta  + lane * 8);
    float4 b1 = *(const float4*)(beta  + lane * 8 + 4);
    const float fv[8] = {
        (a.x - mu) * rs * g0.x + b0.x, (a.y - mu) * rs * g0.y + b0.y,
        (a.z - mu) * rs * g0.z + b0.z, (a.w - mu) * rs * g0.w + b0.w,
        (c.x - mu) * rs * g1.x + b1.x, (c.y - mu) * rs * g1.y + b1.y,
        (c.z - mu) * rs * g1.z + b1.z, (c.w - mu) * rs * g1.w + b1.w };
    ushort8 h, l;
    #pragma unroll
    for (int j = 0; j < 8; ++j) {
        const unsigned short hv = f2bf(fv[j]);
        h[j] = hv; l[j] = f2bf(fv[j] - bf2f(hv));
    }
    *(ushort8*)(xh + (size_t)row * DIM_ + lane * 8) = h;
    *(ushort8*)(xl + (size_t)row * DIM_ + lane * 8) = l;
}

// ---------------- Kernel 1b: W [512][1536] -> W^T split bf16 [1536][512] ----------------
__global__ __launch_bounds__(256) void wsplit_kernel(const float* __restrict__ W,
                                                     unsigned short* __restrict__ Bh,
                                                     unsigned short* __restrict__ Bl) {
    __shared__ float T[64][65];
    const int n0 = blockIdx.x * 64, k0 = blockIdx.y * 64;
    const int tid = threadIdx.x;
    #pragma unroll
    for (int e = 0; e < 4; ++e) {
        const int lin = e * 256 + tid;
        const int kk = lin >> 4;
        const int n4 = (lin & 15) * 4;
        float4 f = *(const float4*)(W + (size_t)(k0 + kk) * QKVW + n0 + n4);
        T[kk][n4 + 0] = f.x; T[kk][n4 + 1] = f.y;
        T[kk][n4 + 2] = f.z; T[kk][n4 + 3] = f.w;
    }
    __syncthreads();
    #pragma unroll
    for (int e = 0; e < 4; ++e) {
        const int lin = e * 256 + tid;
        const int nn = lin >> 4;
        const int kq = (lin & 15) * 4;
        ushort4 h, l;
        float f;
        f = T[kq + 0][nn]; h.x = f2bf(f); l.x = f2bf(f - bf2f(h.x));
        f = T[kq + 1][nn]; h.y = f2bf(f); l.y = f2bf(f - bf2f(h.y));
        f = T[kq + 2][nn]; h.z = f2bf(f); l.z = f2bf(f - bf2f(h.z));
        f = T[kq + 3][nn]; h.w = f2bf(f); l.w = f2bf(f - bf2f(h.w));
        *(ushort4*)(Bh + (size_t)(n0 + nn) * DIM_ + k0 + kq) = h;
        *(ushort4*)(Bl + (size_t)(n0 + nn) * DIM_ + k0 + kq) = l;
    }
}

// ---------------- Kernel 2: MFMA GEMM, split-bf16, async staging, fused repack ----
// Q/K col-blocks: 3-pass (hi*hi + lo*hi + hi*lo). V col-blocks (blockIdx.x>=8):
// 1-pass hi*hi (V output is bf16-rounded anyway). global_load_lds staging.
__global__ __launch_bounds__(256) void gemm_mfma(const unsigned short* __restrict__ Ah,
                                                 const unsigned short* __restrict__ Al,
                                                 const unsigned short* __restrict__ Bh,
                                                 const unsigned short* __restrict__ Bl,
                                                 unsigned short* __restrict__ Qh,
                                                 unsigned short* __restrict__ Ql,
                                                 unsigned short* __restrict__ Kh,
                                                 unsigned short* __restrict__ Kl,
                                                 unsigned short* __restrict__ Vt) {
    __shared__ __attribute__((aligned(16))) unsigned short sAh[128 * 32], sAl[128 * 32];
    __shared__ __attribute__((aligned(16))) unsigned short sBh[128 * 32], sBl[128 * 32];
    const int tid  = threadIdx.x;
    const int lane = tid & 63, wave = tid >> 6;
    const int wr = wave >> 1, wc = wave & 1;
    const int lg = lane >> 4, l16 = lane & 15;
    const int row0 = blockIdx.y * 128;
    const int col0 = blockIdx.x * 128;
    const int part = col0 >> 9;                  // 0=Q, 1=K, 2=V (block-uniform)

    f32x4 acc[4][4] = {};

    for (int k0 = 0; k0 < DIM_; k0 += 32) {
        __syncthreads();
        // async staging: idx = s0 + lane; lds elem offset = idx*8 (linear in lane)
        #pragma unroll
        for (int e = 0; e < 2; ++e) {
            const int s0 = e * 256 + wave * 64;
            const int idx = s0 + lane;
            const int r  = idx >> 2;
            const int k8 = (idx & 3) * 8;
            const size_t ga = (size_t)(row0 + r) * DIM_ + k0 + k8;
            const size_t gb = (size_t)(col0 + r) * DIM_ + k0 + k8;
            async_copy16(&sAh[s0 * 8], Ah + ga);
            async_copy16(&sBh[s0 * 8], Bh + gb);
            if (part < 2) {
                async_copy16(&sAl[s0 * 8], Al + ga);
                async_copy16(&sBl[s0 * 8], Bl + gb);
            }
        }
        __syncthreads();   // compiler drains vmcnt(0) before barrier

        const int kb = lg * 8;
        bf16x8 ah[4], bh[4];
        #pragma unroll
        for (int mi = 0; mi < 4; ++mi)
            ah[mi] = *(const bf16x8*)&sAh[(wr * 64 + mi * 16 + l16) * 32 + kb];
        #pragma unroll
        for (int ni = 0; ni < 4; ++ni)
            bh[ni] = *(const bf16x8*)&sBh[(wc * 64 + ni * 16 + l16) * 32 + kb];
        if (part < 2) {
            bf16x8 al[4], bl[4];
            #pragma unroll
            for (int mi = 0; mi < 4; ++mi)
                al[mi] = *(const bf16x8*)&sAl[(wr * 64 + mi * 16 + l16) * 32 + kb];
            #pragma unroll
            for (int ni = 0; ni < 4; ++ni)
                bl[ni] = *(const bf16x8*)&sBl[(wc * 64 + ni * 16 + l16) * 32 + kb];
            #pragma unroll
            for (int mi = 0; mi < 4; ++mi)
                #pragma unroll
                for (int ni = 0; ni < 4; ++ni) {
                    acc[mi][ni] = __builtin_amdgcn_mfma_f32_16x16x32_bf16(ah[mi], bh[ni], acc[mi][ni], 0, 0, 0);
                    acc[mi][ni] = __builtin_amdgcn_mfma_f32_16x16x32_bf16(al[mi], bh[ni], acc[mi][ni], 0, 0, 0);
                    acc[mi][ni] = __builtin_amdgcn_mfma_f32_16x16x32_bf16(ah[mi], bl[ni], acc[mi][ni], 0, 0, 0);
                }
        } else {
            #pragma unroll
            for (int mi = 0; mi < 4; ++mi)
                #pragma unroll
                for (int ni = 0; ni < 4; ++ni)
                    acc[mi][ni] = __builtin_amdgcn_mfma_f32_16x16x32_bf16(ah[mi], bh[ni], acc[mi][ni], 0, 0, 0);
        }
    }

    // ---- fused repack epilogue (C/D: col = l16, row = lg*4 + rr) ----
    const int colbase = col0 + wc * 64;
    const int head = (colbase & 511) >> 6;       // wave-uniform
    if (part < 2) {
        unsigned short* __restrict__ Ih = (part == 0) ? Qh : Kh;
        unsigned short* __restrict__ Il = (part == 0) ? Ql : Kl;
        #pragma unroll
        for (int mi = 0; mi < 4; ++mi) {
            const int rb = row0 + wr * 64 + mi * 16 + lg * 4;
            const int n  = rb & 2047;
            const size_t tbase = ((size_t)((rb >> 11) * H_ + head) * 32 + (n >> 6)) * 4096;
            #pragma unroll
            for (int ni = 0; ni < 4; ++ni) {
                const int d  = ni * 16 + l16;
                const int k8 = d >> 3;
                #pragma unroll
                for (int rr = 0; rr < 4; ++rr) {
                    const int r = (n & 63) + rr;
                    const size_t off = tbase + r * 64 + ((k8 ^ (r & 7)) * 8) + (d & 7);
                    const float v = acc[mi][ni][rr];
                    const unsigned short hv = f2bf(v);
                    Ih[off] = hv;
                    Il[off] = f2bf(v - bf2f(hv));
                }
            }
        }
    } else {
        #pragma unroll
        for (int mi = 0; mi < 4; ++mi) {
            const int rb = row0 + wr * 64 + mi * 16 + lg * 4;
            const int n  = rb & 2047;
            const size_t cbase = ((size_t)((rb >> 11) * H_ + head) * 32 + (n >> 6)) * 4096;
            const int nr = n & 63;
            #pragma unroll
            for (int ni = 0; ni < 4; ++ni) {
                const int d = ni * 16 + l16;
                const size_t off = cbase + d * 64 + (((nr >> 3) ^ (d & 7)) * 8) + (nr & 7);
                ushort4 pk;
                pk.x = f2bf(acc[mi][ni][0]); pk.y = f2bf(acc[mi][ni][1]);
                pk.z = f2bf(acc[mi][ni][2]); pk.w = f2bf(acc[mi][ni][3]);
                *(ushort4*)&Vt[off] = pk;
            }
        }
    }
}

// ---------------- Kernel 3: banded attention, MFMA, async-staged images ----------------
__global__ __launch_bounds__(256) void attn_mfma(const unsigned short* __restrict__ Qh,
                                                 const unsigned short* __restrict__ Ql,
                                                 const unsigned short* __restrict__ Kh,
                                                 const unsigned short* __restrict__ Kl,
                                                 const unsigned short* __restrict__ Vt,
                                                 float* __restrict__ out) {
    const int tile = blockIdx.x, h = blockIdx.y, b = blockIdx.z;
    const int i0   = tile * 64;
    const int tid  = threadIdx.x;
    const int lane = tid & 63, wave = tid >> 6;
    const int lg   = lane >> 4, l16 = lane & 15;

    __shared__ __attribute__((aligned(16))) unsigned short sKh[4096], sKl[4096], sVt[4096];
    __shared__ __attribute__((aligned(16))) unsigned short sP[4][1024];

    const size_t hb = (size_t)(b * H_ + h) * 32;

    // ---- Q fragments straight from the swizzled tile image ----
    bf16x8 qh[2], ql[2];
    {
        const int r = wave * 16 + l16;
        const size_t tb = (hb + tile) * 4096;
        #pragma unroll
        for (int kh = 0; kh < 2; ++kh) {
            const size_t off = tb + r * 64 + (((kh * 4 + lg) ^ (r & 7)) * 8);
            qh[kh] = *(const bf16x8*)(Qh + off);
            ql[kh] = *(const bf16x8*)(Ql + off);
        }
    }

    float m_run[4], l_run[4];
    f32x4 oacc[4] = {};
    #pragma unroll
    for (int r = 0; r < 4; ++r) { m_run[r] = -1e30f; l_run[r] = 0.0f; }

    #pragma unroll 1
    for (int c = 0; c < 5; ++c) {
        const int jbase = i0 - 128 + c * 64;
        if (jbase + 64 <= 0 || jbase >= N_) continue;
        __syncthreads();
        // ---- async-stage K(hi/lo) + V^T images: lds offset linear in lane ----
        const size_t kbG = (hb + (jbase >> 6)) * 4096;
        #pragma unroll
        for (int e = 0; e < 6; ++e) {
            const int s0  = e * 256 + wave * 64;        // 64-aligned run
            const int arr = s0 >> 9;                    // wave-uniform
            const int w0  = (s0 & 511) * 8;             // lds elem base
            unsigned short* dst = (arr == 0) ? sKh : (arr == 1) ? sKl : sVt;
            const unsigned short* src = (arr == 0) ? Kh : (arr == 1) ? Kl : Vt;
            async_copy16(dst + w0, src + kbG + w0 + lane * 8);
        }
        __syncthreads();   // drains vmcnt(0)

        // ---- S = Q K^T (3-pass split) ----
        f32x4 sacc[4] = {};
        #pragma unroll
        for (int kh = 0; kh < 2; ++kh) {
            #pragma unroll
            for (int t = 0; t < 4; ++t) {
                const int r = t * 16 + l16;
                const int off = r * 64 + ((((kh * 4 + lg)) ^ (r & 7)) * 8);
                const bf16x8 kbh = *(const bf16x8*)&sKh[off];
                const bf16x8 kbl = *(const bf16x8*)&sKl[off];
                sacc[t] = __builtin_amdgcn_mfma_f32_16x16x32_bf16(qh[kh], kbh, sacc[t], 0, 0, 0);
                sacc[t] = __builtin_amdgcn_mfma_f32_16x16x32_bf16(ql[kh], kbh, sacc[t], 0, 0, 0);
                sacc[t] = __builtin_amdgcn_mfma_f32_16x16x32_bf16(qh[kh], kbl, sacc[t], 0, 0, 0);
            }
        }

        // ---- online softmax; P -> per-wave LDS (bf16, swizzled) ----
        #pragma unroll
        for (int r = 0; r < 4; ++r) {
            const int i = i0 + wave * 16 + lg * 4 + r;
            float sv[4];
            float mx = -1e30f;
            #pragma unroll
            for (int t = 0; t < 4; ++t) {
                const int j = jbase + t * 16 + l16;
                const int d = j - i;
                const bool ok = (d >= -BAND_) && (d < BAND_);
                sv[t] = ok ? sacc[t][r] : -1e30f;
                mx = fmaxf(mx, sv[t]);
            }
            #pragma unroll
            for (int o = 1; o < 16; o <<= 1) mx = fmaxf(mx, __shfl_xor(mx, o));
            const float m_new = fmaxf(m_run[r], mx);
            const float alpha = __expf(m_run[r] - m_new);
            float p[4], lc = 0.f;
            #pragma unroll
            for (int t = 0; t < 4; ++t) { p[t] = __expf(sv[t] - m_new); lc += p[t]; }
            #pragma unroll
            for (int o = 1; o < 16; o <<= 1) lc += __shfl_xor(lc, o);
            l_run[r] = l_run[r] * alpha + lc;
            m_run[r] = m_new;
            #pragma unroll
            for (int dt = 0; dt < 4; ++dt) oacc[dt][r] *= alpha;
            const int q = lg * 4 + r;
            #pragma unroll
            for (int t = 0; t < 4; ++t) {
                const int k = t * 16 + l16;
                sP[wave][q * 64 + (((k >> 3) ^ (q & 7)) * 8) + (k & 7)] = f2bf(p[t]);
            }
        }

        // ---- O += P V ----
        #pragma unroll
        for (int kh = 0; kh < 2; ++kh) {
            const int poff = l16 * 64 + ((((kh * 4 + lg)) ^ (l16 & 7)) * 8);
            const bf16x8 pa = *(const bf16x8*)&sP[wave][poff];
            #pragma unroll
            for (int dt = 0; dt < 4; ++dt) {
                const int rv = dt * 16 + l16;
                const int voff = rv * 64 + ((((kh * 4 + lg)) ^ (rv & 7)) * 8);
                const bf16x8 vb = *(const bf16x8*)&sVt[voff];
                oacc[dt] = __builtin_amdgcn_mfma_f32_16x16x32_bf16(pa, vb, oacc[dt], 0, 0, 0);
            }
        }
    }

    // ---- epilogue ----
    #pragma unroll
    for (int dt = 0; dt < 4; ++dt)
        #pragma unroll
        for (int r = 0; r < 4; ++r) {
            const int i = i0 + wave * 16 + lg * 4 + r;
            out[((size_t)b * N_ + i) * DIM_ + h * DH_ + dt * 16 + l16] = oacc[dt][r] / l_run[r];
        }
}

extern "C" void kernel_launch(void* const* d_in, const int* in_sizes, int n_in,
                              void* d_out, int out_size, void* d_ws, size_t ws_size,
                              hipStream_t stream) {
    const float* x     = (const float*)d_in[0];
    const float* w     = (const float*)d_in[1];
    const float* gamma = (const float*)d_in[2];
    const float* beta  = (const float*)d_in[3];
    float* out = (float*)d_out;

    const size_t NTOK = (size_t)B_ * N_;             // 4096
    const size_t IMG  = (size_t)B_ * H_ * 32 * 4096; // u16 per image

    unsigned short* xnh = (unsigned short*)d_ws;
    unsigned short* xnl = xnh + NTOK * DIM_;
    unsigned short* wth = xnl + NTOK * DIM_;
    unsigned short* wtl = wth + (size_t)QKVW * DIM_;
    unsigned short* Qh  = wtl + (size_t)QKVW * DIM_;
    unsigned short* Ql  = Qh + IMG;
    unsigned short* Kh  = Ql + IMG;
    unsigned short* Kl  = Kh + IMG;
    unsigned short* Vt  = Kl + IMG;

    ln_kernel<<<dim3((B_ * N_) / 4), dim3(256), 0, stream>>>(x, gamma, beta, xnh, xnl);
    wsplit_kernel<<<dim3(QKVW / 64, DIM_ / 64), dim3(256), 0, stream>>>(w, wth, wtl);
    gemm_mfma<<<dim3(QKVW / 128, (B_ * N_) / 128), dim3(256), 0, stream>>>(
        xnh, xnl, wth, wtl, Qh, Ql, Kh, Kl, Vt);
    attn_mfma<<<dim3(N_ / 64, H_, B_), dim3(256), 0, stream>>>(Qh, Ql, Kh, Kl, Vt, out);
}